// Round 2
// baseline (465.015 us; speedup 1.0000x reference)
//
#include <hip/hip_runtime.h>
#include <hip/hip_bf16.h>
#include <math.h>

// Problem constants
#define NB 16          // batch
#define NS 4           // seq (new tokens)
#define NN 2048        // model dim
#define ND 128         // head dim
#define NH 16          // heads
#define NM 4096        // cache length
#define NCHK 8         // M-chunks for split attention
#define CHROWS 512     // rows per chunk (NM/NCHK)

// Workspace layout (float offsets)
#define XN_OFF   0u           // [64][2048] normalized X
#define Q_OFF    131072u      // [64][2048]
#define K_OFF    262144u      // [64][2048] new K rows
#define V_OFF    393216u      // [64][2048] new V rows
#define OP_OFF   524288u      // [256 bh][8 ch][4 q][128 d] partial O (unnormalized)
#define ML_OFF   1572864u     // [256 bh][8 ch][4 q][2] (max, sumexp)
// total 1589248 floats = ~6.4 MB

// ---------------------------------------------------------------- RMSNorm
__global__ __launch_bounds__(256) void k_rmsnorm(const float* __restrict__ X,
                                                 float* __restrict__ ws) {
    const int row = blockIdx.x;        // 0..63
    const int tid = threadIdx.x;       // 256
    const float* xr = X + (size_t)row * NN;
    float4 a = *(const float4*)(xr + tid * 4);
    float4 b = *(const float4*)(xr + 1024 + tid * 4);
    float ss = a.x*a.x + a.y*a.y + a.z*a.z + a.w*a.w
             + b.x*b.x + b.y*b.y + b.z*b.z + b.w*b.w;
    #pragma unroll
    for (int off = 32; off; off >>= 1) ss += __shfl_xor(ss, off);
    __shared__ float ls[4];
    if ((tid & 63) == 0) ls[tid >> 6] = ss;
    __syncthreads();
    const float r = rsqrtf((ls[0] + ls[1] + ls[2] + ls[3]) * (1.0f / NN));
    float* o = ws + XN_OFF + (size_t)row * NN;
    *(float4*)(o + tid * 4)        = make_float4(a.x*r, a.y*r, a.z*r, a.w*r);
    *(float4*)(o + 1024 + tid * 4) = make_float4(b.x*r, b.y*r, b.z*r, b.w*r);
}

// ------------------------------------------------- QKV projection (f32 GEMM)
// grid: (256 col-tiles of 8, 3 weights). block 256 = 64 rows x 4 colgroups(2 cols)
__global__ __launch_bounds__(256) void k_qkv(const float* __restrict__ Wq,
                                             const float* __restrict__ Wk,
                                             const float* __restrict__ Wv,
                                             float* __restrict__ ws) {
    __shared__ float xs[64][68];   // [row][kk], pad 68 keeps b128 alignment
    const int which = blockIdx.y;
    const float* __restrict__ W = (which == 0) ? Wq : (which == 1) ? Wk : Wv;
    float* out = ws + Q_OFF + (size_t)which * 131072u;
    const int c0  = blockIdx.x * 8;
    const int tid = threadIdx.x;
    const int cg  = tid & 3;
    const int row = tid >> 2;
    const int cc  = c0 + cg * 2;
    const float* xn = ws + XN_OFF;
    float2 acc = make_float2(0.f, 0.f);
    for (int k0 = 0; k0 < NN; k0 += 64) {
        __syncthreads();
        #pragma unroll
        for (int i = 0; i < 4; i++) {
            int idx = tid + i * 256;         // float4 index within 64x64 chunk
            int r  = idx >> 4;
            int kq = (idx & 15) * 4;
            *(float4*)&xs[r][kq] = *(const float4*)(xn + (size_t)r * NN + k0 + kq);
        }
        __syncthreads();
        #pragma unroll
        for (int kk4 = 0; kk4 < 16; kk4++) {
            float4 xv = *(const float4*)&xs[row][kk4 * 4];
            const float* wp = W + (size_t)(k0 + kk4 * 4) * NN + cc;
            float2 w0 = *(const float2*)(wp);
            float2 w1 = *(const float2*)(wp + NN);
            float2 w2 = *(const float2*)(wp + 2 * NN);
            float2 w3 = *(const float2*)(wp + 3 * NN);
            acc.x += xv.x * w0.x; acc.y += xv.x * w0.y;
            acc.x += xv.y * w1.x; acc.y += xv.y * w1.y;
            acc.x += xv.z * w2.x; acc.y += xv.z * w2.y;
            acc.x += xv.w * w3.x; acc.y += xv.w * w3.y;
        }
    }
    *(float2*)(out + (size_t)row * NN + cc) = acc;
}

// ---------------------------------------- split-M flash attention partials
// grid: (8 chunks, 16 h, 16 b). block 256 = 4 waves; each lane owns one K row
// per 64-row tile (phase A: scores), then lanes own d-pairs (phase B: P*V).
__global__ __launch_bounds__(256) void k_attn(const float* __restrict__ cK,
                                              const float* __restrict__ cV,
                                              const int* __restrict__ Pp,
                                              float* __restrict__ ws) {
    const int ch = blockIdx.x, h = blockIdx.y, b = blockIdx.z;
    const int tid = threadIdx.x;
    const int wv = tid >> 6, lane = tid & 63;
    const int P = *Pp;
    __shared__ float Qs[4 * 128];
    __shared__ float ps[4][64][4];     // per-wave p values (scaled)
    __shared__ float Ow[4][4][128];    // per-wave O partials
    __shared__ float mlw[4][4][2];     // per-wave (max, sumexp)
    if (tid < 128) {
        int q = tid >> 5, d = (tid & 31) * 4;
        *(float4*)&Qs[q * 128 + d] =
            *(const float4*)(ws + Q_OFF + (size_t)(b * 4 + q) * NN + h * 128 + d);
    }
    __syncthreads();

    float m_run[4], l_l[4], Oa[4][2];
    #pragma unroll
    for (int q = 0; q < 4; q++) {
        m_run[q] = -INFINITY; l_l[q] = 0.f; Oa[q][0] = 0.f; Oa[q][1] = 0.f;
    }
    const float* kbase = cK + (size_t)(b * NH + h) * NM * ND;
    const float* vbase = cV + (size_t)(b * NH + h) * NM * ND;
    const float* knew = ws + K_OFF;
    const float* vnew = ws + V_OFF;

    for (int t = 0; t < 2; t++) {
        const int mb = ch * CHROWS + (t * 4 + wv) * 64;
        const int mrow = mb + lane;
        const bool fresh = (mrow >= P) && (mrow < P + NS);
        const float* kp = fresh ? (knew + (size_t)(b * 4 + (mrow - P)) * NN + h * 128)
                                : (kbase + (size_t)mrow * ND);
        float s0 = 0.f, s1 = 0.f, s2 = 0.f, s3 = 0.f;
        #pragma unroll 8
        for (int d4 = 0; d4 < 32; d4++) {
            float4 k4 = *(const float4*)(kp + d4 * 4);
            float4 q0 = *(const float4*)&Qs[0 * 128 + d4 * 4];
            float4 q1 = *(const float4*)&Qs[1 * 128 + d4 * 4];
            float4 q2 = *(const float4*)&Qs[2 * 128 + d4 * 4];
            float4 q3 = *(const float4*)&Qs[3 * 128 + d4 * 4];
            s0 += q0.x*k4.x + q0.y*k4.y + q0.z*k4.z + q0.w*k4.w;
            s1 += q1.x*k4.x + q1.y*k4.y + q1.z*k4.z + q1.w*k4.w;
            s2 += q2.x*k4.x + q2.y*k4.y + q2.z*k4.z + q2.w*k4.w;
            s3 += q3.x*k4.x + q3.y*k4.y + q3.z*k4.z + q3.w*k4.w;
        }
        float s[4] = {s0, s1, s2, s3};
        float smax[4] = {s0, s1, s2, s3};
        #pragma unroll
        for (int off = 32; off; off >>= 1) {
            #pragma unroll
            for (int q = 0; q < 4; q++)
                smax[q] = fmaxf(smax[q], __shfl_xor(smax[q], off));
        }
        float p[4], fac[4];
        #pragma unroll
        for (int q = 0; q < 4; q++) {
            float mn = fmaxf(m_run[q], smax[q]);
            fac[q] = __expf(m_run[q] - mn);
            m_run[q] = mn;
            p[q] = __expf(s[q] - mn);
            l_l[q] = l_l[q] * fac[q] + p[q];
            Oa[q][0] *= fac[q];
            Oa[q][1] *= fac[q];
        }
        *(float4*)&ps[wv][lane][0] = make_float4(p[0], p[1], p[2], p[3]);
        __syncthreads();   // safety: ensure ps visible before phase-B reads
        // phase B: lanes own d-pair; iterate rows, p broadcast from LDS
        #pragma unroll 4
        for (int r = 0; r < 64; r++) {
            const int mr = mb + r;
            const bool fr2 = (mr >= P) && (mr < P + NS);
            const float* vp = fr2 ? (vnew + (size_t)(b * 4 + (mr - P)) * NN + h * 128)
                                  : (vbase + (size_t)mr * ND);
            float2 v2 = *(const float2*)(vp + lane * 2);
            float4 pr = *(const float4*)&ps[wv][r][0];
            Oa[0][0] += pr.x * v2.x; Oa[0][1] += pr.x * v2.y;
            Oa[1][0] += pr.y * v2.x; Oa[1][1] += pr.y * v2.y;
            Oa[2][0] += pr.z * v2.x; Oa[2][1] += pr.z * v2.y;
            Oa[3][0] += pr.w * v2.x; Oa[3][1] += pr.w * v2.y;
        }
        __syncthreads();   // safety: phase-B reads done before next tile's write
    }
    // sum l across the wave
    #pragma unroll
    for (int off = 32; off; off >>= 1) {
        #pragma unroll
        for (int q = 0; q < 4; q++) l_l[q] += __shfl_xor(l_l[q], off);
    }
    #pragma unroll
    for (int q = 0; q < 4; q++)
        *(float2*)&Ow[wv][q][lane * 2] = make_float2(Oa[q][0], Oa[q][1]);
    if (lane == 0) {
        #pragma unroll
        for (int q = 0; q < 4; q++) { mlw[wv][q][0] = m_run[q]; mlw[wv][q][1] = l_l[q]; }
    }
    __syncthreads();
    // combine the 4 wave partials -> one chunk partial
    const int q = tid >> 6;
    const int d0 = lane * 2;
    float ms = fmaxf(fmaxf(mlw[0][q][0], mlw[1][q][0]),
                     fmaxf(mlw[2][q][0], mlw[3][q][0]));
    float o0 = 0.f, o1 = 0.f, lsum = 0.f;
    #pragma unroll
    for (int w2 = 0; w2 < 4; w2++) {
        float e = __expf(mlw[w2][q][0] - ms);
        o0 += e * Ow[w2][q][d0];
        o1 += e * Ow[w2][q][d0 + 1];
        lsum += e * mlw[w2][q][1];
    }
    const size_t bh = (size_t)(b * NH + h);
    const size_t pidx = ((bh * NCHK + ch) * 4 + q) * 128 + d0;
    ws[OP_OFF + pidx] = o0;
    ws[OP_OFF + pidx + 1] = o1;
    if (lane == 0) {
        const size_t mi = ((bh * NCHK + ch) * 4 + q) * 2;
        ws[ML_OFF + mi] = ms;
        ws[ML_OFF + mi + 1] = lsum;
    }
}

// --------------------------------------------- final combine over chunks
// Output is FLOAT32 (reference output dtype is f32; d_out is float*).
__global__ __launch_bounds__(256) void k_comb(const float* __restrict__ ws,
                                              float* __restrict__ out) {
    const int bh = blockIdx.x;           // 0..255
    const int b = bh >> 4, h = bh & 15;
    const int tid = threadIdx.x;
    const int q = tid >> 6, d0 = (tid & 63) * 2;
    float ms = -INFINITY;
    #pragma unroll
    for (int c = 0; c < NCHK; c++)
        ms = fmaxf(ms, ws[ML_OFF + (((size_t)bh * NCHK + c) * 4 + q) * 2]);
    float o0 = 0.f, o1 = 0.f, den = 0.f;
    #pragma unroll
    for (int c = 0; c < NCHK; c++) {
        const size_t mi = (((size_t)bh * NCHK + c) * 4 + q) * 2;
        float e = __expf(ws[ML_OFF + mi] - ms);
        den += e * ws[ML_OFF + mi + 1];
        const size_t pi = (((size_t)bh * NCHK + c) * 4 + q) * 128 + d0;
        o0 += e * ws[OP_OFF + pi];
        o1 += e * ws[OP_OFF + pi + 1];
    }
    const float inv = 1.0f / den;
    const size_t oi = (size_t)(b * 4 + q) * NN + h * 128 + d0;
    *(float2*)(out + oi) = make_float2(o0 * inv, o1 * inv);
}

// ----------------------------------------------------------------- launch
extern "C" void kernel_launch(void* const* d_in, const int* in_sizes, int n_in,
                              void* d_out, int out_size, void* d_ws, size_t ws_size,
                              hipStream_t stream) {
    const float* X  = (const float*)d_in[0];
    const float* Wq = (const float*)d_in[1];
    const float* Wk = (const float*)d_in[2];
    const float* Wv = (const float*)d_in[3];
    const float* cK = (const float*)d_in[4];
    const float* cV = (const float*)d_in[5];
    const int*   Pp = (const int*)d_in[6];
    float* ws = (float*)d_ws;
    float* out = (float*)d_out;

    hipLaunchKernelGGL(k_rmsnorm, dim3(64), dim3(256), 0, stream, X, ws);
    hipLaunchKernelGGL(k_qkv, dim3(256, 3), dim3(256), 0, stream, Wq, Wk, Wv, ws);
    hipLaunchKernelGGL(k_attn, dim3(NCHK, NH, NB), dim3(256), 0, stream, cK, cV, Pp, ws);
    hipLaunchKernelGGL(k_comb, dim3(NB * NH), dim3(256), 0, stream, ws, out);
}

// Round 3
// 265.707 us; speedup vs baseline: 1.7501x; 1.7501x over previous
//
#include <hip/hip_runtime.h>
#include <hip/hip_bf16.h>
#include <math.h>

// Problem constants
#define NB 16          // batch
#define NS 4           // seq (new tokens)
#define NN 2048        // model dim
#define ND 128         // head dim
#define NH 16          // heads
#define NM 4096        // cache length
#define NCHK 8         // M-chunks for split attention
#define CHROWS 512     // rows per chunk (NM/NCHK)

// Workspace layout (float offsets)
#define XN_OFF   0u           // [64][2048] normalized X
#define Q_OFF    131072u      // [64][2048]
#define K_OFF    262144u      // [64][2048] new K rows
#define V_OFF    393216u      // [64][2048] new V rows
#define OP_OFF   524288u      // [256 bh][8 ch][4 q][128 d] partial O
#define ML_OFF   1572864u     // [256 bh][8 ch][4 q][2] (max, sumexp)
#define PART_OFF 1589248u     // [8 kc][3 which][64][2048] QKV partials

// ---------------------------------------------------------------- RMSNorm
__global__ __launch_bounds__(256) void k_rmsnorm(const float* __restrict__ X,
                                                 float* __restrict__ ws) {
    const int row = blockIdx.x;        // 0..63
    const int tid = threadIdx.x;
    const float* xr = X + (size_t)row * NN;
    float4 a = *(const float4*)(xr + tid * 4);
    float4 b = *(const float4*)(xr + 1024 + tid * 4);
    float ss = a.x*a.x + a.y*a.y + a.z*a.z + a.w*a.w
             + b.x*b.x + b.y*b.y + b.z*b.z + b.w*b.w;
    #pragma unroll
    for (int off = 32; off; off >>= 1) ss += __shfl_xor(ss, off);
    __shared__ float ls[4];
    if ((tid & 63) == 0) ls[tid >> 6] = ss;
    __syncthreads();
    const float r = rsqrtf((ls[0] + ls[1] + ls[2] + ls[3]) * (1.0f / NN));
    float* o = ws + XN_OFF + (size_t)row * NN;
    *(float4*)(o + tid * 4)        = make_float4(a.x*r, a.y*r, a.z*r, a.w*r);
    *(float4*)(o + 1024 + tid * 4) = make_float4(b.x*r, b.y*r, b.z*r, b.w*r);
}

// -------------------------------------------- QKV projection (tiled f32 GEMM)
// grid (16 col-tiles of 128, 3 which, 8 k-chunks of 256). block 256.
// Per block: 64x128 output partial over 256 k. LDS: XnT[64k][64r], W[64k][128c].
__global__ __launch_bounds__(256) void k_qkv(const float* __restrict__ Wq,
                                             const float* __restrict__ Wk,
                                             const float* __restrict__ Wv,
                                             float* __restrict__ ws) {
    __shared__ float xsT[64][68];    // [kk][row] (+pad, 272B row = 16B-aligned)
    __shared__ float wt[64][132];    // [kk][col] (+pad, 528B row = 16B-aligned)
    const int ct    = blockIdx.x;    // col tile (128 cols)
    const int which = blockIdx.y;    // 0..2
    const int kc    = blockIdx.z;    // 0..7
    const float* __restrict__ W = (which == 0) ? Wq : (which == 1) ? Wk : Wv;
    const int tid = threadIdx.x;
    const int c0  = ct * 128;
    const int rg  = tid >> 5;        // 0..7 (8 rows each)
    const int cg  = tid & 31;        // 0..31 (4 cols each)
    const float* xn = ws + XN_OFF;

    float4 acc[8];
    #pragma unroll
    for (int i = 0; i < 8; i++) acc[i] = make_float4(0.f, 0.f, 0.f, 0.f);

    for (int s = 0; s < 4; s++) {
        const int k0 = kc * 256 + s * 64;
        __syncthreads();
        // stage Xn 64x64 transposed: thread: row r=tid>>2, 4 float4 along k
        {
            const int r  = tid >> 2;
            const int q4 = tid & 3;
            #pragma unroll
            for (int i = 0; i < 4; i++) {
                const int f4 = q4 + i * 4;                 // 0..15
                float4 v = *(const float4*)(xn + (size_t)r * NN + k0 + f4 * 4);
                xsT[f4 * 4 + 0][r] = v.x;
                xsT[f4 * 4 + 1][r] = v.y;
                xsT[f4 * 4 + 2][r] = v.z;
                xsT[f4 * 4 + 3][r] = v.w;
            }
        }
        // stage W 64x128: 8 iters, per iter wave covers 2 rows x 512B contig
        {
            #pragma unroll
            for (int j8 = 0; j8 < 8; j8++) {
                const int kk  = j8 * 8 + (tid >> 5);
                const int f4c = tid & 31;
                float4 v = *(const float4*)(W + (size_t)(k0 + kk) * NN + c0 + f4c * 4);
                *(float4*)&wt[kk][f4c * 4] = v;
            }
        }
        __syncthreads();
        #pragma unroll 8
        for (int kk = 0; kk < 64; kk++) {
            const float4 x0 = *(const float4*)&xsT[kk][rg * 8];
            const float4 x1 = *(const float4*)&xsT[kk][rg * 8 + 4];
            const float4 w4 = *(const float4*)&wt[kk][cg * 4];
            acc[0].x += x0.x*w4.x; acc[0].y += x0.x*w4.y; acc[0].z += x0.x*w4.z; acc[0].w += x0.x*w4.w;
            acc[1].x += x0.y*w4.x; acc[1].y += x0.y*w4.y; acc[1].z += x0.y*w4.z; acc[1].w += x0.y*w4.w;
            acc[2].x += x0.z*w4.x; acc[2].y += x0.z*w4.y; acc[2].z += x0.z*w4.z; acc[2].w += x0.z*w4.w;
            acc[3].x += x0.w*w4.x; acc[3].y += x0.w*w4.y; acc[3].z += x0.w*w4.z; acc[3].w += x0.w*w4.w;
            acc[4].x += x1.x*w4.x; acc[4].y += x1.x*w4.y; acc[4].z += x1.x*w4.z; acc[4].w += x1.x*w4.w;
            acc[5].x += x1.y*w4.x; acc[5].y += x1.y*w4.y; acc[5].z += x1.y*w4.z; acc[5].w += x1.y*w4.w;
            acc[6].x += x1.z*w4.x; acc[6].y += x1.z*w4.y; acc[6].z += x1.z*w4.z; acc[6].w += x1.z*w4.w;
            acc[7].x += x1.w*w4.x; acc[7].y += x1.w*w4.y; acc[7].z += x1.w*w4.z; acc[7].w += x1.w*w4.w;
        }
    }
    float* po = ws + PART_OFF + (size_t)(kc * 3 + which) * 131072u;
    #pragma unroll
    for (int i = 0; i < 8; i++)
        *(float4*)(po + (size_t)(rg * 8 + i) * NN + c0 + cg * 4) = acc[i];
}

// ------------------------------------------ sum the 8 k-chunk partials
__global__ __launch_bounds__(256) void k_reduce(float* __restrict__ ws) {
    const int idx = blockIdx.x * 256 + threadIdx.x;    // f4 index, 98304 total
    const int which = idx >> 15;                       // /32768
    const int off   = idx & 32767;                     // f4 within [64][2048]
    float4 s = make_float4(0.f, 0.f, 0.f, 0.f);
    #pragma unroll
    for (int kcc = 0; kcc < 8; kcc++) {
        const float4 v = *(const float4*)(ws + PART_OFF
                         + (size_t)(kcc * 3 + which) * 131072u + (size_t)off * 4);
        s.x += v.x; s.y += v.y; s.z += v.z; s.w += v.w;
    }
    *(float4*)(ws + Q_OFF + (size_t)which * 131072u + (size_t)off * 4) = s;
}

// ---------------------------------------- split-M flash attention partials
// grid (8 ch, 16 h, 16 b), block 256 = 4 waves.
// K tiles (64x128 f32) staged to LDS double-buffered via global_load_lds,
// XOR-swizzled (granule ^= row&7) to kill the same-column bank conflict.
// Phase A: wave w computes scores for q=w, lane=row. Phase B: wave w handles
// rows [w*16,w*16+16) for all 4 q; V read direct from global (coalesced).
__global__ __launch_bounds__(256) void k_attn(const float* __restrict__ cK,
                                              const float* __restrict__ cV,
                                              const int* __restrict__ Pp,
                                              float* __restrict__ ws) {
    const int ch = blockIdx.x, h = blockIdx.y, b = blockIdx.z;
    const int tid = threadIdx.x;
    const int wv = tid >> 6, lane = tid & 63;
    const int P = *Pp;
    __shared__ float Ks[2][64 * 128];              // 64KB, double-buffered
    __shared__ float Qs[4][128] __attribute__((aligned(16)));
    __shared__ float ps[64][4] __attribute__((aligned(16)));
    __shared__ float facs[4] __attribute__((aligned(16)));
    __shared__ float Ow[4][4][128];
    __shared__ float mls[4][2];

    if (tid < 128) {
        const int q = tid >> 5, d = (tid & 31) * 4;
        *(float4*)&Qs[q][d] =
            *(const float4*)(ws + Q_OFF + (size_t)(b * 4 + q) * NN + h * 128 + d);
    }

    const float* kbase = cK + (size_t)(b * NH + h) * NM * ND;
    const float* vbase = cV + (size_t)(b * NH + h) * NM * ND;
    const float* knew  = ws + K_OFF;
    const float* vnew  = ws + V_OFF;
    const int mb0 = ch * CHROWS;

    // stage tile tt into buffer bufi: 32 wave-issues of 64 lanes x 16B
    auto STAGE = [&](int tt, int bufi) {
        const int mb = mb0 + tt * 64;
        #pragma unroll
        for (int i = 0; i < 8; i++) {
            const int g0  = (wv * 8 + i) * 64;     // granule base (wave-uniform)
            const int g   = g0 + lane;
            const int row = g >> 5;
            const int c4  = g & 31;
            const int csw = c4 ^ (row & 7);        // source pre-swizzle
            const int mrow = mb + row;
            const float* src;
            if (mrow >= P && mrow < P + NS)
                src = knew + (size_t)(b * 4 + (mrow - P)) * NN + h * 128 + csw * 4;
            else
                src = kbase + (size_t)mrow * ND + csw * 4;
            __builtin_amdgcn_global_load_lds(
                (const __attribute__((address_space(1))) void*)src,
                (__attribute__((address_space(3))) void*)(&Ks[bufi][g0 * 4]),
                16, 0, 0);
        }
    };

    float m_run = -INFINITY, l_run = 0.f;
    float2 Oa[4];
    #pragma unroll
    for (int q = 0; q < 4; q++) Oa[q] = make_float2(0.f, 0.f);

    STAGE(0, 0);
    __syncthreads();   // drains vmcnt -> tile 0 ready (and Qs visible)

    for (int t = 0; t < 8; t++) {
        const int cur = t & 1;
        if (t < 7) STAGE(t + 1, cur ^ 1);          // in flight across phases A+B

        // ---- phase A: score for q=wv, row=lane (swizzled LDS reads)
        const float* kr = &Ks[cur][lane * 128];
        const int s7 = lane & 7;
        float s = 0.f;
        #pragma unroll
        for (int d4 = 0; d4 < 32; d4++) {
            const float4 k4 = *(const float4*)&kr[(d4 ^ s7) * 4];
            const float4 q4 = *(const float4*)&Qs[wv][d4 * 4];
            s += k4.x*q4.x + k4.y*q4.y + k4.z*q4.z + k4.w*q4.w;
        }
        float wm = s;
        #pragma unroll
        for (int off = 32; off; off >>= 1) wm = fmaxf(wm, __shfl_xor(wm, off));
        const float mn  = fmaxf(m_run, wm);
        const float fac = __expf(m_run - mn);
        m_run = mn;
        const float p = __expf(s - mn);
        l_run = l_run * fac + p;
        ps[lane][wv] = p;
        if (lane == 0) facs[wv] = fac;
        // LDS-only sync (leave staged global loads in flight)
        asm volatile("s_waitcnt lgkmcnt(0)" ::: "memory");
        __builtin_amdgcn_s_barrier();
        __builtin_amdgcn_sched_barrier(0);

        // ---- phase B: wave wv does rows r0..r0+15 for all q
        const float4 fq = *(const float4*)&facs[0];
        Oa[0].x *= fq.x; Oa[0].y *= fq.x;
        Oa[1].x *= fq.y; Oa[1].y *= fq.y;
        Oa[2].x *= fq.z; Oa[2].y *= fq.z;
        Oa[3].x *= fq.w; Oa[3].y *= fq.w;
        const int r0 = wv * 16;
        #pragma unroll 4
        for (int r = 0; r < 16; r++) {
            const int mr = mb0 + t * 64 + r0 + r;
            const float* vp = (mr >= P && mr < P + NS)
                            ? vnew + (size_t)(b * 4 + (mr - P)) * NN + h * 128
                            : vbase + (size_t)mr * ND;
            const float2 v2 = *(const float2*)(vp + lane * 2);
            const float4 pr = *(const float4*)&ps[r0 + r][0];
            Oa[0].x += pr.x * v2.x; Oa[0].y += pr.x * v2.y;
            Oa[1].x += pr.y * v2.x; Oa[1].y += pr.y * v2.y;
            Oa[2].x += pr.z * v2.x; Oa[2].y += pr.z * v2.y;
            Oa[3].x += pr.w * v2.x; Oa[3].y += pr.w * v2.y;
        }
        __syncthreads();   // full drain: next tile staged + ps reads done
    }

    // wave-sum l (rows partitioned across lanes)
    #pragma unroll
    for (int off = 32; off; off >>= 1) l_run += __shfl_xor(l_run, off);
    #pragma unroll
    for (int q = 0; q < 4; q++)
        *(float2*)&Ow[wv][q][lane * 2] = Oa[q];
    if (lane == 0) { mls[wv][0] = m_run; mls[wv][1] = l_run; }
    __syncthreads();

    // block combine: plain sum across waves (same m/l sequence per q)
    const int q = wv;
    const int d0 = lane * 2;
    float o0 = 0.f, o1 = 0.f;
    #pragma unroll
    for (int w2 = 0; w2 < 4; w2++) {
        o0 += Ow[w2][q][d0];
        o1 += Ow[w2][q][d0 + 1];
    }
    const size_t bh = (size_t)(b * NH + h);
    const size_t pidx = ((bh * NCHK + ch) * 4 + q) * 128 + d0;
    ws[OP_OFF + pidx]     = o0;
    ws[OP_OFF + pidx + 1] = o1;
    if (lane == 0) {
        const size_t mi = ((bh * NCHK + ch) * 4 + q) * 2;
        ws[ML_OFF + mi]     = mls[q][0];
        ws[ML_OFF + mi + 1] = mls[q][1];
    }
}

// --------------------------------------------- final combine over chunks
__global__ __launch_bounds__(256) void k_comb(const float* __restrict__ ws,
                                              float* __restrict__ out) {
    const int bh = blockIdx.x;           // 0..255
    const int b = bh >> 4, h = bh & 15;
    const int tid = threadIdx.x;
    const int q = tid >> 6, d0 = (tid & 63) * 2;
    float ms = -INFINITY;
    #pragma unroll
    for (int c = 0; c < NCHK; c++)
        ms = fmaxf(ms, ws[ML_OFF + (((size_t)bh * NCHK + c) * 4 + q) * 2]);
    float o0 = 0.f, o1 = 0.f, den = 0.f;
    #pragma unroll
    for (int c = 0; c < NCHK; c++) {
        const size_t mi = (((size_t)bh * NCHK + c) * 4 + q) * 2;
        float e = __expf(ws[ML_OFF + mi] - ms);
        den += e * ws[ML_OFF + mi + 1];
        const size_t pi = (((size_t)bh * NCHK + c) * 4 + q) * 128 + d0;
        o0 += e * ws[OP_OFF + pi];
        o1 += e * ws[OP_OFF + pi + 1];
    }
    const float inv = 1.0f / den;
    const size_t oi = (size_t)(b * 4 + q) * NN + h * 128 + d0;
    *(float2*)(out + oi) = make_float2(o0 * inv, o1 * inv);
}

// ----------------------------------------------------------------- launch
extern "C" void kernel_launch(void* const* d_in, const int* in_sizes, int n_in,
                              void* d_out, int out_size, void* d_ws, size_t ws_size,
                              hipStream_t stream) {
    const float* X  = (const float*)d_in[0];
    const float* Wq = (const float*)d_in[1];
    const float* Wk = (const float*)d_in[2];
    const float* Wv = (const float*)d_in[3];
    const float* cK = (const float*)d_in[4];
    const float* cV = (const float*)d_in[5];
    const int*   Pp = (const int*)d_in[6];
    float* ws = (float*)d_ws;
    float* out = (float*)d_out;

    hipLaunchKernelGGL(k_rmsnorm, dim3(64), dim3(256), 0, stream, X, ws);
    hipLaunchKernelGGL(k_qkv, dim3(16, 3, 8), dim3(256), 0, stream, Wq, Wk, Wv, ws);
    hipLaunchKernelGGL(k_reduce, dim3(384), dim3(256), 0, stream, ws);
    hipLaunchKernelGGL(k_attn, dim3(NCHK, NH, NB), dim3(256), 0, stream, cK, cV, Pp, ws);
    hipLaunchKernelGGL(k_comb, dim3(NB * NH), dim3(256), 0, stream, ws, out);
}

// Round 4
// 238.179 us; speedup vs baseline: 1.9524x; 1.1156x over previous
//
#include <hip/hip_runtime.h>
#include <hip/hip_bf16.h>
#include <math.h>

// Problem constants
#define NB 16          // batch
#define NS 4           // seq (new tokens)
#define NN 2048        // model dim
#define ND 128         // head dim
#define NH 16          // heads
#define NM 4096        // cache length
#define NCHK 8         // M-chunks for split attention
#define CHROWS 512     // rows per chunk (NM/NCHK)
#define TROWS 32       // rows per K/V tile
#define NT 16          // tiles per chunk (CHROWS/TROWS)
#define NKC 16         // k-chunks for QKV split-k

// Workspace layout (float offsets)
#define XN_OFF   0u           // [64][2048] normalized X
#define Q_OFF    131072u      // [64][2048]
#define K_OFF    262144u      // [64][2048] new K rows
#define V_OFF    393216u      // [64][2048] new V rows
#define OP_OFF   524288u      // [256 bh][8 ch][4 q][128 d] partial O
#define ML_OFF   1572864u     // [256 bh][8 ch][4 q][2] (max, sumexp)
#define PART_OFF 1589248u     // [16 kc][3 which][64][2048] QKV partials (~25MB)

// ---------------------------------------------------------------- RMSNorm
__global__ __launch_bounds__(256) void k_rmsnorm(const float* __restrict__ X,
                                                 float* __restrict__ ws) {
    const int row = blockIdx.x;        // 0..63
    const int tid = threadIdx.x;
    const float* xr = X + (size_t)row * NN;
    float4 a = *(const float4*)(xr + tid * 4);
    float4 b = *(const float4*)(xr + 1024 + tid * 4);
    float ss = a.x*a.x + a.y*a.y + a.z*a.z + a.w*a.w
             + b.x*b.x + b.y*b.y + b.z*b.z + b.w*b.w;
    #pragma unroll
    for (int off = 32; off; off >>= 1) ss += __shfl_xor(ss, off);
    __shared__ float ls[4];
    if ((tid & 63) == 0) ls[tid >> 6] = ss;
    __syncthreads();
    const float r = rsqrtf((ls[0] + ls[1] + ls[2] + ls[3]) * (1.0f / NN));
    float* o = ws + XN_OFF + (size_t)row * NN;
    *(float4*)(o + tid * 4)        = make_float4(a.x*r, a.y*r, a.z*r, a.w*r);
    *(float4*)(o + 1024 + tid * 4) = make_float4(b.x*r, b.y*r, b.z*r, b.w*r);
}

// -------------------------------------------- QKV projection (tiled f32 GEMM)
// grid (16 col-tiles of 128, 3 which, 16 k-chunks of 128). block 256.
__global__ __launch_bounds__(256) void k_qkv(const float* __restrict__ Wq,
                                             const float* __restrict__ Wk,
                                             const float* __restrict__ Wv,
                                             float* __restrict__ ws) {
    __shared__ float xsT[64][68];    // [kk][row] (+pad)
    __shared__ float wt[64][132];    // [kk][col] (+pad)
    const int ct    = blockIdx.x;    // col tile (128 cols)
    const int which = blockIdx.y;    // 0..2
    const int kc    = blockIdx.z;    // 0..15
    const float* __restrict__ W = (which == 0) ? Wq : (which == 1) ? Wk : Wv;
    const int tid = threadIdx.x;
    const int c0  = ct * 128;
    const int rg  = tid >> 5;        // 0..7 (8 rows each)
    const int cg  = tid & 31;        // 0..31 (4 cols each)
    const float* xn = ws + XN_OFF;

    float4 acc[8];
    #pragma unroll
    for (int i = 0; i < 8; i++) acc[i] = make_float4(0.f, 0.f, 0.f, 0.f);

    for (int s = 0; s < 2; s++) {
        const int k0 = kc * 128 + s * 64;
        __syncthreads();
        // stage Xn 64x64 transposed
        {
            const int r  = tid >> 2;
            const int q4 = tid & 3;
            #pragma unroll
            for (int i = 0; i < 4; i++) {
                const int f4 = q4 + i * 4;                 // 0..15
                float4 v = *(const float4*)(xn + (size_t)r * NN + k0 + f4 * 4);
                xsT[f4 * 4 + 0][r] = v.x;
                xsT[f4 * 4 + 1][r] = v.y;
                xsT[f4 * 4 + 2][r] = v.z;
                xsT[f4 * 4 + 3][r] = v.w;
            }
        }
        // stage W 64x128: per iter 8 rows x 512B contiguous
        {
            #pragma unroll
            for (int j8 = 0; j8 < 8; j8++) {
                const int kk  = j8 * 8 + (tid >> 5);
                const int f4c = tid & 31;
                float4 v = *(const float4*)(W + (size_t)(k0 + kk) * NN + c0 + f4c * 4);
                *(float4*)&wt[kk][f4c * 4] = v;
            }
        }
        __syncthreads();
        #pragma unroll 8
        for (int kk = 0; kk < 64; kk++) {
            const float4 x0 = *(const float4*)&xsT[kk][rg * 8];
            const float4 x1 = *(const float4*)&xsT[kk][rg * 8 + 4];
            const float4 w4 = *(const float4*)&wt[kk][cg * 4];
            acc[0].x += x0.x*w4.x; acc[0].y += x0.x*w4.y; acc[0].z += x0.x*w4.z; acc[0].w += x0.x*w4.w;
            acc[1].x += x0.y*w4.x; acc[1].y += x0.y*w4.y; acc[1].z += x0.y*w4.z; acc[1].w += x0.y*w4.w;
            acc[2].x += x0.z*w4.x; acc[2].y += x0.z*w4.y; acc[2].z += x0.z*w4.z; acc[2].w += x0.z*w4.w;
            acc[3].x += x0.w*w4.x; acc[3].y += x0.w*w4.y; acc[3].z += x0.w*w4.z; acc[3].w += x0.w*w4.w;
            acc[4].x += x1.x*w4.x; acc[4].y += x1.x*w4.y; acc[4].z += x1.x*w4.z; acc[4].w += x1.x*w4.w;
            acc[5].x += x1.y*w4.x; acc[5].y += x1.y*w4.y; acc[5].z += x1.y*w4.z; acc[5].w += x1.y*w4.w;
            acc[6].x += x1.z*w4.x; acc[6].y += x1.z*w4.y; acc[6].z += x1.z*w4.z; acc[6].w += x1.z*w4.w;
            acc[7].x += x1.w*w4.x; acc[7].y += x1.w*w4.y; acc[7].z += x1.w*w4.z; acc[7].w += x1.w*w4.w;
        }
    }
    float* po = ws + PART_OFF + (size_t)(kc * 3 + which) * 131072u;
    #pragma unroll
    for (int i = 0; i < 8; i++)
        *(float4*)(po + (size_t)(rg * 8 + i) * NN + c0 + cg * 4) = acc[i];
}

// ------------------------------------------ sum the 16 k-chunk partials
__global__ __launch_bounds__(256) void k_reduce(float* __restrict__ ws) {
    const int idx = blockIdx.x * 256 + threadIdx.x;    // f4 index, 98304 total
    const int which = idx >> 15;                       // /32768
    const int off   = idx & 32767;                     // f4 within [64][2048]
    float4 s = make_float4(0.f, 0.f, 0.f, 0.f);
    #pragma unroll
    for (int kcc = 0; kcc < NKC; kcc++) {
        const float4 v = *(const float4*)(ws + PART_OFF
                         + (size_t)(kcc * 3 + which) * 131072u + (size_t)off * 4);
        s.x += v.x; s.y += v.y; s.z += v.z; s.w += v.w;
    }
    *(float4*)(ws + Q_OFF + (size_t)which * 131072u + (size_t)off * 4) = s;
}

// ---------------------------------------- split-M flash attention partials
// grid (8 ch, 16 h, 16 b), block 256 = 4 waves. 32-row K/V tiles, both staged
// via global_load_lds, double-buffered. K XOR-swizzled (c4 ^= row&7) on both
// sides; V linear (phase-B reads are row-contiguous -> conflict-free).
// Phase A: wave w scores q=w; lane = (half d, row). Phase B: wave w rows
// [w*8, w*8+8) for all 4 q, V from LDS.
__global__ __launch_bounds__(256) void k_attn(const float* __restrict__ cK,
                                              const float* __restrict__ cV,
                                              const int* __restrict__ Pp,
                                              float* __restrict__ ws) {
    const int ch = blockIdx.x, h = blockIdx.y, b = blockIdx.z;
    const int tid = threadIdx.x;
    const int wv = tid >> 6, lane = tid & 63;
    const int half = lane >> 5, r32 = lane & 31;
    const int P = *Pp;
    __shared__ float Ks[2][TROWS * 128];           // 32KB
    __shared__ float Vs[2][TROWS * 128];           // 32KB
    __shared__ float Qs[4][128] __attribute__((aligned(16)));
    __shared__ float ps[TROWS][4] __attribute__((aligned(16)));
    __shared__ float facs[4] __attribute__((aligned(16)));
    __shared__ float Ow[4][4][128];
    __shared__ float mls[4][2];

    if (tid < 128) {
        const int q = tid >> 5, d = (tid & 31) * 4;
        *(float4*)&Qs[q][d] =
            *(const float4*)(ws + Q_OFF + (size_t)(b * 4 + q) * NN + h * 128 + d);
    }

    const float* kbase = cK + (size_t)(b * NH + h) * NM * ND;
    const float* vbase = cV + (size_t)(b * NH + h) * NM * ND;
    const float* knew  = ws + K_OFF;
    const float* vnew  = ws + V_OFF;
    const int mb0 = ch * CHROWS;

    // stage tile tt (K swizzled + V linear) into buffer bufi; 8 issues/wave
    auto STAGE = [&](int tt, int bufi) {
        const int mb = mb0 + tt * TROWS;
        #pragma unroll
        for (int i = 0; i < 4; i++) {
            const int g0  = (wv * 4 + i) * 64;     // granule group base
            const int g   = g0 + lane;
            const int row = g >> 5;
            const int c4  = g & 31;
            const int csw = c4 ^ (row & 7);
            const int mrow = mb + row;
            const float* src = (mrow >= P && mrow < P + NS)
                ? knew + (size_t)(b * 4 + (mrow - P)) * NN + h * 128 + csw * 4
                : kbase + (size_t)mrow * ND + csw * 4;
            __builtin_amdgcn_global_load_lds(
                (const __attribute__((address_space(1))) void*)src,
                (__attribute__((address_space(3))) void*)(&Ks[bufi][g0 * 4]),
                16, 0, 0);
        }
        #pragma unroll
        for (int i = 0; i < 4; i++) {
            const int g0  = (wv * 4 + i) * 64;
            const int g   = g0 + lane;
            const int row = g >> 5;
            const int c4  = g & 31;
            const int mrow = mb + row;
            const float* src = (mrow >= P && mrow < P + NS)
                ? vnew + (size_t)(b * 4 + (mrow - P)) * NN + h * 128 + c4 * 4
                : vbase + (size_t)mrow * ND + c4 * 4;
            __builtin_amdgcn_global_load_lds(
                (const __attribute__((address_space(1))) void*)src,
                (__attribute__((address_space(3))) void*)(&Vs[bufi][g0 * 4]),
                16, 0, 0);
        }
    };

    float m_run = -INFINITY, l_run = 0.f;
    float2 Oa[4];
    #pragma unroll
    for (int q = 0; q < 4; q++) Oa[q] = make_float2(0.f, 0.f);

    STAGE(0, 0);
    __syncthreads();   // vmcnt(0) drain: tile 0 ready, Qs visible

    for (int t = 0; t < NT; t++) {
        const int cur = t & 1;
        if (t < NT - 1) STAGE(t + 1, cur ^ 1);     // in flight across A+B

        // ---- phase A: q=wv; lane computes half-dot for row r32
        const int s7 = r32 & 7;
        const float* kr = &Ks[cur][r32 * 128 + half * 64];
        const float* qr = &Qs[wv][half * 64];
        float s = 0.f;
        #pragma unroll
        for (int j = 0; j < 16; j++) {
            const float4 k4 = *(const float4*)&kr[(j ^ s7) * 4];
            const float4 q4 = *(const float4*)&qr[j * 4];
            s += k4.x*q4.x + k4.y*q4.y + k4.z*q4.z + k4.w*q4.w;
        }
        s += __shfl_xor(s, 32);                    // combine halves
        float wm = s;
        #pragma unroll
        for (int off = 16; off; off >>= 1) wm = fmaxf(wm, __shfl_xor(wm, off));
        const float mn  = fmaxf(m_run, wm);
        const float fac = __expf(m_run - mn);
        m_run = mn;
        const float p = __expf(s - mn);
        l_run = l_run * fac + ((half == 0) ? p : 0.f);
        if (half == 0) ps[r32][wv] = p;
        if (lane == 0) facs[wv] = fac;
        // LDS-only sync; staged global loads stay in flight
        asm volatile("s_waitcnt lgkmcnt(0)" ::: "memory");
        __builtin_amdgcn_s_barrier();
        __builtin_amdgcn_sched_barrier(0);

        // ---- phase B: wave wv rows [wv*8, wv*8+8), V from LDS
        const float4 fq = *(const float4*)&facs[0];
        Oa[0].x *= fq.x; Oa[0].y *= fq.x;
        Oa[1].x *= fq.y; Oa[1].y *= fq.y;
        Oa[2].x *= fq.z; Oa[2].y *= fq.z;
        Oa[3].x *= fq.w; Oa[3].y *= fq.w;
        const int r0 = wv * 8;
        #pragma unroll
        for (int rr = 0; rr < 8; rr++) {
            const float2 v2 = *(const float2*)&Vs[cur][(r0 + rr) * 128 + lane * 2];
            const float4 pr = *(const float4*)&ps[r0 + rr][0];
            Oa[0].x += pr.x * v2.x; Oa[0].y += pr.x * v2.y;
            Oa[1].x += pr.y * v2.x; Oa[1].y += pr.y * v2.y;
            Oa[2].x += pr.z * v2.x; Oa[2].y += pr.z * v2.y;
            Oa[3].x += pr.w * v2.x; Oa[3].y += pr.w * v2.y;
        }
        __syncthreads();   // full drain: next tile staged + ps reads done
    }

    // l sum across lanes (half-1 lanes carry 0 contributions)
    #pragma unroll
    for (int off = 32; off; off >>= 1) l_run += __shfl_xor(l_run, off);
    #pragma unroll
    for (int q = 0; q < 4; q++)
        *(float2*)&Ow[wv][q][lane * 2] = Oa[q];
    if (lane == 0) { mls[wv][0] = m_run; mls[wv][1] = l_run; }
    __syncthreads();

    // block combine: plain sum across waves (same per-q scale sequence)
    const int q = wv;
    const int d0 = lane * 2;
    float o0 = 0.f, o1 = 0.f;
    #pragma unroll
    for (int w2 = 0; w2 < 4; w2++) {
        o0 += Ow[w2][q][d0];
        o1 += Ow[w2][q][d0 + 1];
    }
    const size_t bh = (size_t)(b * NH + h);
    const size_t pidx = ((bh * NCHK + ch) * 4 + q) * 128 + d0;
    ws[OP_OFF + pidx]     = o0;
    ws[OP_OFF + pidx + 1] = o1;
    if (lane == 0) {
        const size_t mi = ((bh * NCHK + ch) * 4 + q) * 2;
        ws[ML_OFF + mi]     = mls[q][0];
        ws[ML_OFF + mi + 1] = mls[q][1];
    }
}

// --------------------------------------------- final combine over chunks
__global__ __launch_bounds__(256) void k_comb(const float* __restrict__ ws,
                                              float* __restrict__ out) {
    const int bh = blockIdx.x;           // 0..255
    const int b = bh >> 4, h = bh & 15;
    const int tid = threadIdx.x;
    const int q = tid >> 6, d0 = (tid & 63) * 2;
    float ms = -INFINITY;
    #pragma unroll
    for (int c = 0; c < NCHK; c++)
        ms = fmaxf(ms, ws[ML_OFF + (((size_t)bh * NCHK + c) * 4 + q) * 2]);
    float o0 = 0.f, o1 = 0.f, den = 0.f;
    #pragma unroll
    for (int c = 0; c < NCHK; c++) {
        const size_t mi = (((size_t)bh * NCHK + c) * 4 + q) * 2;
        float e = __expf(ws[ML_OFF + mi] - ms);
        den += e * ws[ML_OFF + mi + 1];
        const size_t pi = (((size_t)bh * NCHK + c) * 4 + q) * 128 + d0;
        o0 += e * ws[OP_OFF + pi];
        o1 += e * ws[OP_OFF + pi + 1];
    }
    const float inv = 1.0f / den;
    const size_t oi = (size_t)(b * 4 + q) * NN + h * 128 + d0;
    *(float2*)(out + oi) = make_float2(o0 * inv, o1 * inv);
}

// ----------------------------------------------------------------- launch
extern "C" void kernel_launch(void* const* d_in, const int* in_sizes, int n_in,
                              void* d_out, int out_size, void* d_ws, size_t ws_size,
                              hipStream_t stream) {
    const float* X  = (const float*)d_in[0];
    const float* Wq = (const float*)d_in[1];
    const float* Wk = (const float*)d_in[2];
    const float* Wv = (const float*)d_in[3];
    const float* cK = (const float*)d_in[4];
    const float* cV = (const float*)d_in[5];
    const int*   Pp = (const int*)d_in[6];
    float* ws = (float*)d_ws;
    float* out = (float*)d_out;

    hipLaunchKernelGGL(k_rmsnorm, dim3(64), dim3(256), 0, stream, X, ws);
    hipLaunchKernelGGL(k_qkv, dim3(16, 3, NKC), dim3(256), 0, stream, Wq, Wk, Wv, ws);
    hipLaunchKernelGGL(k_reduce, dim3(384), dim3(256), 0, stream, ws);
    hipLaunchKernelGGL(k_attn, dim3(NCHK, NH, NB), dim3(256), 0, stream, cK, cV, Pp, ws);
    hipLaunchKernelGGL(k_comb, dim3(NB * NH), dim3(256), 0, stream, ws, out);
}